// Round 4
// baseline (5688.602 us; speedup 1.0000x reference)
//
#include <hip/hip_runtime.h>
#include <cfloat>
#include <cmath>

// Problem constants
#define SN 8
#define DN 64
#define KN 512
#define NN 16384            // B*T
#define REPAIR_THR 1e-2f    // fp32 d2 noise ~1e-5; 1000x margin
#define MAXFLAG 65536

// workspace layout (float indices)
#define WS_CNT 0
#define WS_SCL 16
#define WS_OFF (16 + SN*DN)           // 528
#define WS_E2  (WS_OFF + SN*DN)       // 1040
#define WS_ENT (WS_E2 + SN*KN)        // 5136 (ints)
#define WS_X   (WS_ENT + MAXFLAG)     // 70672
#define WS_W   (WS_X + NN*DN)         // +1048576
#define WS_E   (WS_W + SN*DN*DN)      // +32768
#define WS_B   (WS_E + SN*KN*DN)      // +262144
#define WS_G   (WS_B + SN*DN)
#define WS_BE  (WS_G + SN*DN)
#define WS_M   (WS_BE + SN*DN)
#define WS_V   (WS_M + SN*DN)
#define WS_TOT (WS_V + SN*DN)

// ---------------------------------------------------------------- prep ------
__global__ void prep_kernel(const float* __restrict__ b, const float* __restrict__ gamma,
                            const float* __restrict__ beta, const float* __restrict__ bmean,
                            const float* __restrict__ bvar, const float* __restrict__ E,
                            float* __restrict__ ws) {
    int tid = blockIdx.x * 256 + threadIdx.x;
    if (tid < SN * KN) {                       // ||E_k||^2 in fp64, stored fp32
        const float* er = E + (size_t)tid * DN;
        double a = 0.0;
        for (int d = 0; d < DN; ++d) { double v = (double)er[d]; a = fma(v, v, a); }
        ws[WS_E2 + tid] = (float)a;
    }
    int u = tid - SN * KN;
    if (u >= 0 && u < SN * DN) {               // fold BN+bias: bn = proj*scl + off
        double inv = 1.0 / sqrt((double)bvar[u] + 0.001);
        double sc  = (double)gamma[u] * inv;
        ws[WS_SCL + u] = (float)sc;
        ws[WS_OFF + u] = (float)(((double)b[u] - (double)bmean[u]) * sc + (double)beta[u]);
    }
}

// ---------------------------------------------------------------- main ------
// grid 2048 = (s = bid&7, ntile = bid>>3). Block: 256 thr = 16 tg x 16 lg,
// 64 positions/block, ONE s per block. Reads x/W/E from DEVICE-LOCAL ws copies.
__launch_bounds__(256, 3)
__global__ void main_kernel(const float* __restrict__ x, const float* __restrict__ W,
                            const float* __restrict__ E, float* __restrict__ ws,
                            float* __restrict__ out, int entcap) {
    __shared__ float4 A4[2176];        // 34.8 KB union region
    __shared__ float4 zs4[1088];       // 17.4 KB z tile (stride 17)
    __shared__ float scl[64], ofl[64], e2s[128];

    const int tid = threadIdx.x;
    const int tg = tid >> 4;           // 0..15 : owns n = n0 + tg*4 + ti
    const int lg = tid & 15;           // 0..15 : e-cols (C) / k-lanes (D)
    const int s  = blockIdx.x & 7;
    const int n0 = (blockIdx.x >> 3) * 64;

    const float4* xg4 = (const float4*)x;
    const float4* Wg4 = (const float4*)W;
    const float4* Eg4 = (const float4*)E;

    float4* xs4 = A4;                  // 64 rows x stride 17
    float4* ws4 = A4 + 1088;           // 64 rows x stride 16 (broadcast reads)
    float4* es4 = A4;                  // phase D: 128 rows x stride 17

    #pragma unroll
    for (int r = 0; r < 4; ++r) {
        int i = r * 256 + tid;
        xs4[(i >> 4) * 17 + (i & 15)] = xg4[n0 * 16 + i];
        ws4[i] = Wg4[s * 1024 + i];
    }
    if (tid < 64) { scl[tid] = ws[WS_SCL + s * 64 + tid]; ofl[tid] = ws[WS_OFF + s * 64 + tid]; }
    __syncthreads();

    // ---- phase C: proj = x @ W[s]  (4t x 4e per thread) ----
    float pa[4][4];
    #pragma unroll
    for (int ti = 0; ti < 4; ++ti)
        #pragma unroll
        for (int j = 0; j < 4; ++j) pa[ti][j] = 0.f;

    #pragma unroll
    for (int c = 0; c < 16; ++c) {
        float4 xv[4], wv[4];
        #pragma unroll
        for (int ti = 0; ti < 4; ++ti) xv[ti] = xs4[(tg * 4 + ti) * 17 + c];
        #pragma unroll
        for (int dd = 0; dd < 4; ++dd) wv[dd] = ws4[(c * 4 + dd) * 16 + lg];
        #pragma unroll
        for (int ti = 0; ti < 4; ++ti) {
            float a0 = pa[ti][0], a1 = pa[ti][1], a2 = pa[ti][2], a3 = pa[ti][3];
            a0 = fmaf(xv[ti].x, wv[0].x, a0); a0 = fmaf(xv[ti].y, wv[1].x, a0);
            a0 = fmaf(xv[ti].z, wv[2].x, a0); a0 = fmaf(xv[ti].w, wv[3].x, a0);
            a1 = fmaf(xv[ti].x, wv[0].y, a1); a1 = fmaf(xv[ti].y, wv[1].y, a1);
            a1 = fmaf(xv[ti].z, wv[2].y, a1); a1 = fmaf(xv[ti].w, wv[3].y, a1);
            a2 = fmaf(xv[ti].x, wv[0].z, a2); a2 = fmaf(xv[ti].y, wv[1].z, a2);
            a2 = fmaf(xv[ti].z, wv[2].z, a2); a2 = fmaf(xv[ti].w, wv[3].z, a2);
            a3 = fmaf(xv[ti].x, wv[0].w, a3); a3 = fmaf(xv[ti].y, wv[1].w, a3);
            a3 = fmaf(xv[ti].z, wv[2].w, a3); a3 = fmaf(xv[ti].w, wv[3].w, a3);
            pa[ti][0] = a0; pa[ti][1] = a1; pa[ti][2] = a2; pa[ti][3] = a3;
        }
    }

    // ---- BN + softmax (row of 64 across 16 lanes x 4) + z ----
    float s0 = scl[lg * 4 + 0], s1 = scl[lg * 4 + 1], s2 = scl[lg * 4 + 2], s3 = scl[lg * 4 + 3];
    float o0 = ofl[lg * 4 + 0], o1 = ofl[lg * 4 + 1], o2 = ofl[lg * 4 + 2], o3 = ofl[lg * 4 + 3];
    float zz[4];
    #pragma unroll
    for (int ti = 0; ti < 4; ++ti) {
        int t = tg * 4 + ti;
        float v0 = fmaf(pa[ti][0], s0, o0);
        float v1 = fmaf(pa[ti][1], s1, o1);
        float v2 = fmaf(pa[ti][2], s2, o2);
        float v3 = fmaf(pa[ti][3], s3, o3);
        float mx = fmaxf(fmaxf(v0, v1), fmaxf(v2, v3));
        mx = fmaxf(mx, __shfl_xor(mx, 1)); mx = fmaxf(mx, __shfl_xor(mx, 2));
        mx = fmaxf(mx, __shfl_xor(mx, 4)); mx = fmaxf(mx, __shfl_xor(mx, 8));
        float e0 = expf(v0 - mx), e1 = expf(v1 - mx), e2v = expf(v2 - mx), e3 = expf(v3 - mx);
        float sm = e0 + e1 + e2v + e3;
        sm += __shfl_xor(sm, 1); sm += __shfl_xor(sm, 2);
        sm += __shfl_xor(sm, 4); sm += __shfl_xor(sm, 8);
        float inv = 1.0f / sm;
        float4 xv = xs4[t * 17 + lg];
        float z0 = xv.x * (e0 * inv), z1 = xv.y * (e1 * inv);
        float z2 = xv.z * (e2v * inv), z3 = xv.w * (e3 * inv);
        zs4[t * 17 + lg] = make_float4(z0, z1, z2, z3);
        float zv2 = z0 * z0 + z1 * z1 + z2 * z2 + z3 * z3;
        zv2 += __shfl_xor(zv2, 1); zv2 += __shfl_xor(zv2, 2);
        zv2 += __shfl_xor(zv2, 4); zv2 += __shfl_xor(zv2, 8);
        zz[ti] = zv2;
    }
    // zs4 rows used below are written/read by the same 16-lane group (same wave) -> no barrier

    // ---- phase D: scores z@E[s]^T, running (min1,min2,kmin) per t ----
    float m1[4], m2[4]; int k1[4];
    #pragma unroll
    for (int ti = 0; ti < 4; ++ti) { m1[ti] = FLT_MAX; m2[ti] = FLT_MAX; k1[ti] = 0x7fffffff; }

    for (int kk = 0; kk < KN; kk += 128) {
        __syncthreads();                       // all reads of A4 (x/W or prev E chunk) done
        #pragma unroll
        for (int r = 0; r < 8; ++r) {          // stage E chunk (128x64)
            int i = r * 256 + tid;
            es4[(i >> 4) * 17 + (i & 15)] = Eg4[(s * KN + kk) * 16 + i];
        }
        if (tid < 128) e2s[tid] = ws[WS_E2 + s * KN + kk + tid];
        __syncthreads();

        float acc[4][8];
        #pragma unroll
        for (int ti = 0; ti < 4; ++ti)
            #pragma unroll
            for (int j = 0; j < 8; ++j) acc[ti][j] = 0.f;

        #pragma unroll
        for (int c = 0; c < 16; ++c) {
            float4 zv[4], ev[8];
            #pragma unroll
            for (int ti = 0; ti < 4; ++ti) zv[ti] = zs4[(tg * 4 + ti) * 17 + c];
            #pragma unroll
            for (int j = 0; j < 8; ++j) ev[j] = es4[(lg + 16 * j) * 17 + c];
            #pragma unroll
            for (int ti = 0; ti < 4; ++ti) {
                #pragma unroll
                for (int j = 0; j < 8; ++j) {
                    float a = acc[ti][j];
                    a = fmaf(zv[ti].x, ev[j].x, a);
                    a = fmaf(zv[ti].y, ev[j].y, a);
                    a = fmaf(zv[ti].z, ev[j].z, a);
                    a = fmaf(zv[ti].w, ev[j].w, a);
                    acc[ti][j] = a;
                }
            }
        }
        #pragma unroll
        for (int ti = 0; ti < 4; ++ti) {
            #pragma unroll
            for (int j = 0; j < 8; ++j) {
                float d2 = fmaf(-2.0f, acc[ti][j], zz[ti]) + e2s[lg + 16 * j];
                int kx = kk + lg + 16 * j;
                if (d2 < m1[ti]) { m2[ti] = m1[ti]; m1[ti] = d2; k1[ti] = kx; }
                else if (d2 < m2[ti]) { m2[ti] = d2; }
            }
        }
    }

    // cross-lane (16 lanes) lexicographic argmin + second-best merge
    #pragma unroll
    for (int mask = 1; mask <= 8; mask <<= 1) {
        #pragma unroll
        for (int ti = 0; ti < 4; ++ti) {
            float om1 = __shfl_xor(m1[ti], mask);
            int   ok1 = __shfl_xor(k1[ti], mask);
            float om2 = __shfl_xor(m2[ti], mask);
            bool better = (om1 < m1[ti]) || (om1 == m1[ti] && ok1 < k1[ti]);
            float nm2 = better ? fminf(m1[ti], om2) : fminf(om1, m2[ti]);
            if (better) { m1[ti] = om1; k1[ti] = ok1; }
            m2[ti] = nm2;
        }
    }
    if (lg == 0) {
        #pragma unroll
        for (int ti = 0; ti < 4; ++ti) {
            int n = n0 + tg * 4 + ti;
            out[2 * (size_t)NN * DN + s * NN + n] = (float)k1[ti];
            if (m2[ti] - m1[ti] < REPAIR_THR) {   // near-tie -> exact fp64 repair
                int idx = atomicAdd((int*)ws, 1);
                if (idx < entcap) ((int*)ws)[WS_ENT + idx] = (s << 14) | n;
            }
        }
    }
}

// ---------------------------------------------------------------- ze --------
// ze[n] = sum_s x[n] * att_s[n]. Deterministic single write, NO atomics.
__launch_bounds__(256, 4)
__global__ void ze_kernel(const float* __restrict__ x, const float* __restrict__ W,
                          const float* __restrict__ ws, float* __restrict__ out) {
    __shared__ float4 xs4[1088];       // 64 x 17
    __shared__ float4 ws4[1024];       // 64 x 16
    __shared__ float scl[64], ofl[64];

    const int tid = threadIdx.x;
    const int tg = tid >> 4;
    const int lg = tid & 15;
    const int n0 = blockIdx.x * 64;

    const float4* xg4 = (const float4*)x;
    const float4* Wg4 = (const float4*)W;

    #pragma unroll
    for (int r = 0; r < 4; ++r) {
        int i = r * 256 + tid;
        xs4[(i >> 4) * 17 + (i & 15)] = xg4[n0 * 16 + i];
    }

    float4 zea[4];
    #pragma unroll
    for (int ti = 0; ti < 4; ++ti) zea[ti] = make_float4(0.f, 0.f, 0.f, 0.f);

    for (int s = 0; s < SN; ++s) {
        __syncthreads();
        #pragma unroll
        for (int r = 0; r < 4; ++r) {
            int i = r * 256 + tid;
            ws4[i] = Wg4[s * 1024 + i];
        }
        if (tid < 64) { scl[tid] = ws[WS_SCL + s * 64 + tid]; ofl[tid] = ws[WS_OFF + s * 64 + tid]; }
        __syncthreads();

        float pa[4][4];
        #pragma unroll
        for (int ti = 0; ti < 4; ++ti)
            #pragma unroll
            for (int j = 0; j < 4; ++j) pa[ti][j] = 0.f;

        #pragma unroll
        for (int c = 0; c < 16; ++c) {
            float4 xv[4], wv[4];
            #pragma unroll
            for (int ti = 0; ti < 4; ++ti) xv[ti] = xs4[(tg * 4 + ti) * 17 + c];
            #pragma unroll
            for (int dd = 0; dd < 4; ++dd) wv[dd] = ws4[(c * 4 + dd) * 16 + lg];
            #pragma unroll
            for (int ti = 0; ti < 4; ++ti) {
                float a0 = pa[ti][0], a1 = pa[ti][1], a2 = pa[ti][2], a3 = pa[ti][3];
                a0 = fmaf(xv[ti].x, wv[0].x, a0); a0 = fmaf(xv[ti].y, wv[1].x, a0);
                a0 = fmaf(xv[ti].z, wv[2].x, a0); a0 = fmaf(xv[ti].w, wv[3].x, a0);
                a1 = fmaf(xv[ti].x, wv[0].y, a1); a1 = fmaf(xv[ti].y, wv[1].y, a1);
                a1 = fmaf(xv[ti].z, wv[2].y, a1); a1 = fmaf(xv[ti].w, wv[3].y, a1);
                a2 = fmaf(xv[ti].x, wv[0].z, a2); a2 = fmaf(xv[ti].y, wv[1].z, a2);
                a2 = fmaf(xv[ti].z, wv[2].z, a2); a2 = fmaf(xv[ti].w, wv[3].z, a2);
                a3 = fmaf(xv[ti].x, wv[0].w, a3); a3 = fmaf(xv[ti].y, wv[1].w, a3);
                a3 = fmaf(xv[ti].z, wv[2].w, a3); a3 = fmaf(xv[ti].w, wv[3].w, a3);
                pa[ti][0] = a0; pa[ti][1] = a1; pa[ti][2] = a2; pa[ti][3] = a3;
            }
        }

        float s0 = scl[lg * 4 + 0], s1 = scl[lg * 4 + 1], s2 = scl[lg * 4 + 2], s3 = scl[lg * 4 + 3];
        float o0 = ofl[lg * 4 + 0], o1 = ofl[lg * 4 + 1], o2 = ofl[lg * 4 + 2], o3 = ofl[lg * 4 + 3];
        #pragma unroll
        for (int ti = 0; ti < 4; ++ti) {
            int t = tg * 4 + ti;
            float v0 = fmaf(pa[ti][0], s0, o0);
            float v1 = fmaf(pa[ti][1], s1, o1);
            float v2 = fmaf(pa[ti][2], s2, o2);
            float v3 = fmaf(pa[ti][3], s3, o3);
            float mx = fmaxf(fmaxf(v0, v1), fmaxf(v2, v3));
            mx = fmaxf(mx, __shfl_xor(mx, 1)); mx = fmaxf(mx, __shfl_xor(mx, 2));
            mx = fmaxf(mx, __shfl_xor(mx, 4)); mx = fmaxf(mx, __shfl_xor(mx, 8));
            float e0 = expf(v0 - mx), e1 = expf(v1 - mx), e2v = expf(v2 - mx), e3 = expf(v3 - mx);
            float sm = e0 + e1 + e2v + e3;
            sm += __shfl_xor(sm, 1); sm += __shfl_xor(sm, 2);
            sm += __shfl_xor(sm, 4); sm += __shfl_xor(sm, 8);
            float inv = 1.0f / sm;
            float4 xv = xs4[t * 17 + lg];
            zea[ti].x += xv.x * (e0 * inv);
            zea[ti].y += xv.y * (e1 * inv);
            zea[ti].z += xv.z * (e2v * inv);
            zea[ti].w += xv.w * (e3 * inv);
        }
    }

    float4* out4 = (float4*)out;
    #pragma unroll
    for (int ti = 0; ti < 4; ++ti) {
        int n = n0 + tg * 4 + ti;
        out4[(size_t)NN * 16 + n * 16 + lg] = zea[ti];
    }
}

// ---------------------------------------------------------------- repair ----
__global__ void repair_kernel(const float* __restrict__ x, const float* __restrict__ W,
                              const float* __restrict__ b, const float* __restrict__ gamma,
                              const float* __restrict__ beta, const float* __restrict__ bmean,
                              const float* __restrict__ bvar, const float* __restrict__ E,
                              float* __restrict__ ws, float* __restrict__ out, int entcap) {
    __shared__ double zd[64];
    __shared__ double red[256];
    __shared__ int redk[256];
    __shared__ double zzsh;
    int cnt = ((int*)ws)[0]; if (cnt > entcap) cnt = entcap;
    const int tid = threadIdx.x;
    for (int idx = blockIdx.x; idx < cnt; idx += gridDim.x) {
        int code = ((int*)ws)[WS_ENT + idx];
        int s = code >> 14, n = code & (NN - 1);
        int e = tid & 63, q = tid >> 6;
        double p = 0.0;
        for (int d = q * 16; d < q * 16 + 16; ++d)
            p = fma((double)x[n * 64 + d], (double)W[((size_t)s * 64 + d) * 64 + e], p);
        red[tid] = p;
        __syncthreads();
        if (tid < 64) {
            double proj = (red[tid] + red[tid + 64]) + (red[tid + 128] + red[tid + 192]);
            double inv = 1.0 / sqrt((double)bvar[s * 64 + e] + 0.001);
            double bn = (double)gamma[s * 64 + e] * ((proj + (double)b[s * 64 + e]) - (double)bmean[s * 64 + e]) * inv
                      + (double)beta[s * 64 + e];
            zd[e] = bn;
        }
        __syncthreads();
        if (tid == 0) {
            double m = zd[0];
            for (int i = 1; i < 64; ++i) m = fmax(m, zd[i]);
            double sm = 0.0;
            for (int i = 0; i < 64; ++i) { double t = exp(zd[i] - m); zd[i] = t; sm += t; }
            double zzv = 0.0;
            for (int i = 0; i < 64; ++i) { double z = (double)x[n * 64 + i] * (zd[i] / sm); zd[i] = z; zzv = fma(z, z, zzv); }
            zzsh = zzv;
        }
        __syncthreads();
        double bv = DBL_MAX; int bk = 1 << 30;
        for (int k = tid; k < KN; k += 256) {
            const float* er = E + ((size_t)s * KN + k) * 64;
            double dot = 0.0, e2 = 0.0;
            for (int d = 0; d < 64; ++d) { double ed = (double)er[d]; dot = fma(zd[d], ed, dot); e2 = fma(ed, ed, e2); }
            double d2 = (zzsh - 2.0 * dot) + e2;
            if (d2 < bv) { bv = d2; bk = k; }
        }
        red[tid] = bv; redk[tid] = bk;
        __syncthreads();
        if (tid == 0) {
            double m = red[0]; int mk = redk[0];
            for (int i = 1; i < 256; ++i)
                if (red[i] < m || (red[i] == m && redk[i] < mk)) { m = red[i]; mk = redk[i]; }
            out[2 * (size_t)NN * 64 + s * NN + n] = (float)mk;
        }
        __syncthreads();
    }
}

// ---------------------------------------------------------------- gather ----
__global__ void gather_kernel(const float* __restrict__ E, float* __restrict__ out) {
    const int tid = threadIdx.x;
    const int ni = tid >> 4, dq = tid & 15;
    const int n = blockIdx.x * 16 + ni;
    const float4* Eg4 = (const float4*)E;
    float4 a = make_float4(0.f, 0.f, 0.f, 0.f);
    #pragma unroll
    for (int s = 0; s < SN; ++s) {
        int k = (int)(out[2 * (size_t)NN * DN + s * NN + n] + 0.5f);
        float4 e = Eg4[((size_t)s * KN + k) * 16 + dq];
        a.x += e.x; a.y += e.y; a.z += e.z; a.w += e.w;
    }
    ((float4*)out)[(size_t)n * 16 + dq] = a;
}

// ---------------------------------------------------------------- launch ----
extern "C" void kernel_launch(void* const* d_in, const int* in_sizes, int n_in,
                              void* d_out, int out_size, void* d_ws, size_t ws_size,
                              hipStream_t stream) {
    const float* x     = (const float*)d_in[0];
    const float* W     = (const float*)d_in[1];
    const float* b     = (const float*)d_in[2];
    const float* gamma = (const float*)d_in[3];
    const float* beta  = (const float*)d_in[4];
    const float* bmean = (const float*)d_in[5];
    const float* bvar  = (const float*)d_in[6];
    const float* E     = (const float*)d_in[7];
    float* out = (float*)d_out;
    float* ws  = (float*)d_ws;

    // ---- DIAGNOSTIC/FIX: copy all inputs to device-local workspace (d2d, ~5.2 MB).
    // If the input buffers are far/uncached memory, every kernel read was paying
    // PCIe/migration cost; after this, all reads are HBM/L2-local.
    const float *xP = x, *WP = W, *bP = b, *gP = gamma, *beP = beta, *mP = bmean, *vP = bvar, *EP = E;
    bool usecopy = (ws_size / 4) >= (size_t)WS_TOT;
    if (usecopy) {
        hipMemcpyAsync(ws + WS_X,  x,     (size_t)NN * DN * 4,      hipMemcpyDeviceToDevice, stream);
        hipMemcpyAsync(ws + WS_W,  W,     (size_t)SN * DN * DN * 4, hipMemcpyDeviceToDevice, stream);
        hipMemcpyAsync(ws + WS_E,  E,     (size_t)SN * KN * DN * 4, hipMemcpyDeviceToDevice, stream);
        hipMemcpyAsync(ws + WS_B,  b,     (size_t)SN * DN * 4,      hipMemcpyDeviceToDevice, stream);
        hipMemcpyAsync(ws + WS_G,  gamma, (size_t)SN * DN * 4,      hipMemcpyDeviceToDevice, stream);
        hipMemcpyAsync(ws + WS_BE, beta,  (size_t)SN * DN * 4,      hipMemcpyDeviceToDevice, stream);
        hipMemcpyAsync(ws + WS_M,  bmean, (size_t)SN * DN * 4,      hipMemcpyDeviceToDevice, stream);
        hipMemcpyAsync(ws + WS_V,  bvar,  (size_t)SN * DN * 4,      hipMemcpyDeviceToDevice, stream);
        xP = ws + WS_X; WP = ws + WS_W; EP = ws + WS_E; bP = ws + WS_B;
        gP = ws + WS_G; beP = ws + WS_BE; mP = ws + WS_M; vP = ws + WS_V;
    }

    int entcap = MAXFLAG;
    if (!usecopy) {
        long avail = (long)(ws_size / 4) - WS_ENT - 16;
        if (avail < 0) avail = 0;
        entcap = (int)(avail > MAXFLAG ? MAXFLAG : avail);
    }

    hipMemsetAsync(d_ws, 0, 64, stream);                          // zero flag counter
    prep_kernel<<<18, 256, 0, stream>>>(bP, gP, beP, mP, vP, EP, ws);
    main_kernel<<<2048, 256, 0, stream>>>(xP, WP, EP, ws, out, entcap);
    ze_kernel<<<256, 256, 0, stream>>>(xP, WP, ws, out);
    repair_kernel<<<256, 256, 0, stream>>>(xP, WP, bP, gP, beP, mP, vP, EP, ws, out, entcap);
    gather_kernel<<<1024, 256, 0, stream>>>(EP, out);
}

// Round 5
// 5681.154 us; speedup vs baseline: 1.0013x; 1.0013x over previous
//
#include <hip/hip_runtime.h>
#include <cfloat>
#include <cmath>

// Problem constants
#define SN 8
#define DN 64
#define KN 512
#define NN 16384            // B*T
#define REPAIR_THR 1e-2f    // fp32 d2 noise ~1e-5; 1000x margin
#define MAXFLAG 65536

// workspace layout (float indices)
#define WS_CNT 0
#define WS_SCL 16
#define WS_OFF (16 + SN*DN)           // 528
#define WS_E2  (WS_OFF + SN*DN)       // 1040
#define WS_ENT (WS_E2 + SN*KN)        // 5136 (ints)

// ---------------------------------------------------------------- prep ------
__global__ void prep_kernel(const float* __restrict__ b, const float* __restrict__ gamma,
                            const float* __restrict__ beta, const float* __restrict__ bmean,
                            const float* __restrict__ bvar, const float* __restrict__ E,
                            float* __restrict__ ws) {
    int tid = blockIdx.x * 256 + threadIdx.x;
    if (tid < SN * KN) {                       // ||E_k||^2 in fp64, stored fp32
        const float* er = E + (size_t)tid * DN;
        double a = 0.0;
        for (int d = 0; d < DN; ++d) { double v = (double)er[d]; a = fma(v, v, a); }
        ws[WS_E2 + tid] = (float)a;
    }
    int u = tid - SN * KN;
    if (u >= 0 && u < SN * DN) {               // fold BN+bias: bn = proj*scl + off
        double inv = 1.0 / sqrt((double)bvar[u] + 0.001);
        double sc  = (double)gamma[u] * inv;
        ws[WS_SCL + u] = (float)sc;
        ws[WS_OFF + u] = (float)(((double)b[u] - (double)bmean[u]) * sc + (double)beta[u]);
    }
}

// ---------------------------------------------------------------- main ------
// grid 2048 = (s = bid&7, ntile = bid>>3). Block: 256 thr = 16 tg x 16 lg,
// 64 positions/block, ONE s per block.
// amdgpu_waves_per_eu(3,3): pin allocator at 3 waves/EU (VGPR budget 170) so it does
// NOT squeeze to 6 waves/EU and spill acc arrays to scratch (r2-r4: VGPR=84 + 16 GB
// of scratch traffic = the whole 5.5 ms). LDS 53 KB caps us at 3 blocks/CU anyway.
__global__ void __launch_bounds__(256)
__attribute__((amdgpu_waves_per_eu(3, 3)))
main_kernel(const float* __restrict__ x, const float* __restrict__ W,
            const float* __restrict__ E, float* __restrict__ ws,
            float* __restrict__ out, int entcap) {
    __shared__ float4 A4[2176];        // 34.8 KB union region
    __shared__ float4 zs4[1088];       // 17.4 KB z tile (stride 17)
    __shared__ float scl[64], ofl[64], e2s[128];

    const int tid = threadIdx.x;
    const int tg = tid >> 4;           // 0..15 : owns n = n0 + tg*4 + ti
    const int lg = tid & 15;           // 0..15 : e-cols (C) / k-lanes (D)
    const int s  = blockIdx.x & 7;
    const int n0 = (blockIdx.x >> 3) * 64;

    const float4* xg4 = (const float4*)x;
    const float4* Wg4 = (const float4*)W;
    const float4* Eg4 = (const float4*)E;

    float4* xs4 = A4;                  // 64 rows x stride 17
    float4* ws4 = A4 + 1088;           // 64 rows x stride 16 (broadcast reads)
    float4* es4 = A4;                  // phase D: 128 rows x stride 17

    #pragma unroll
    for (int r = 0; r < 4; ++r) {
        int i = r * 256 + tid;
        xs4[(i >> 4) * 17 + (i & 15)] = xg4[n0 * 16 + i];
        ws4[i] = Wg4[s * 1024 + i];
    }
    if (tid < 64) { scl[tid] = ws[WS_SCL + s * 64 + tid]; ofl[tid] = ws[WS_OFF + s * 64 + tid]; }
    __syncthreads();

    // ---- phase C: proj = x @ W[s]  (4t x 4e per thread) ----
    float pa[4][4];
    #pragma unroll
    for (int ti = 0; ti < 4; ++ti)
        #pragma unroll
        for (int j = 0; j < 4; ++j) pa[ti][j] = 0.f;

    #pragma unroll
    for (int c = 0; c < 16; ++c) {
        float4 xv[4], wv[4];
        #pragma unroll
        for (int ti = 0; ti < 4; ++ti) xv[ti] = xs4[(tg * 4 + ti) * 17 + c];
        #pragma unroll
        for (int dd = 0; dd < 4; ++dd) wv[dd] = ws4[(c * 4 + dd) * 16 + lg];
        #pragma unroll
        for (int ti = 0; ti < 4; ++ti) {
            float a0 = pa[ti][0], a1 = pa[ti][1], a2 = pa[ti][2], a3 = pa[ti][3];
            a0 = fmaf(xv[ti].x, wv[0].x, a0); a0 = fmaf(xv[ti].y, wv[1].x, a0);
            a0 = fmaf(xv[ti].z, wv[2].x, a0); a0 = fmaf(xv[ti].w, wv[3].x, a0);
            a1 = fmaf(xv[ti].x, wv[0].y, a1); a1 = fmaf(xv[ti].y, wv[1].y, a1);
            a1 = fmaf(xv[ti].z, wv[2].y, a1); a1 = fmaf(xv[ti].w, wv[3].y, a1);
            a2 = fmaf(xv[ti].x, wv[0].z, a2); a2 = fmaf(xv[ti].y, wv[1].z, a2);
            a2 = fmaf(xv[ti].z, wv[2].z, a2); a2 = fmaf(xv[ti].w, wv[3].z, a2);
            a3 = fmaf(xv[ti].x, wv[0].w, a3); a3 = fmaf(xv[ti].y, wv[1].w, a3);
            a3 = fmaf(xv[ti].z, wv[2].w, a3); a3 = fmaf(xv[ti].w, wv[3].w, a3);
            pa[ti][0] = a0; pa[ti][1] = a1; pa[ti][2] = a2; pa[ti][3] = a3;
        }
    }

    // ---- BN + softmax (row of 64 across 16 lanes x 4) + z ----
    float s0 = scl[lg * 4 + 0], s1 = scl[lg * 4 + 1], s2 = scl[lg * 4 + 2], s3 = scl[lg * 4 + 3];
    float o0 = ofl[lg * 4 + 0], o1 = ofl[lg * 4 + 1], o2 = ofl[lg * 4 + 2], o3 = ofl[lg * 4 + 3];
    float zz[4];
    #pragma unroll
    for (int ti = 0; ti < 4; ++ti) {
        int t = tg * 4 + ti;
        float v0 = fmaf(pa[ti][0], s0, o0);
        float v1 = fmaf(pa[ti][1], s1, o1);
        float v2 = fmaf(pa[ti][2], s2, o2);
        float v3 = fmaf(pa[ti][3], s3, o3);
        float mx = fmaxf(fmaxf(v0, v1), fmaxf(v2, v3));
        mx = fmaxf(mx, __shfl_xor(mx, 1)); mx = fmaxf(mx, __shfl_xor(mx, 2));
        mx = fmaxf(mx, __shfl_xor(mx, 4)); mx = fmaxf(mx, __shfl_xor(mx, 8));
        float e0 = expf(v0 - mx), e1 = expf(v1 - mx), e2v = expf(v2 - mx), e3 = expf(v3 - mx);
        float sm = e0 + e1 + e2v + e3;
        sm += __shfl_xor(sm, 1); sm += __shfl_xor(sm, 2);
        sm += __shfl_xor(sm, 4); sm += __shfl_xor(sm, 8);
        float inv = 1.0f / sm;
        float4 xv = xs4[t * 17 + lg];
        float z0 = xv.x * (e0 * inv), z1 = xv.y * (e1 * inv);
        float z2 = xv.z * (e2v * inv), z3 = xv.w * (e3 * inv);
        zs4[t * 17 + lg] = make_float4(z0, z1, z2, z3);
        float zv2 = z0 * z0 + z1 * z1 + z2 * z2 + z3 * z3;
        zv2 += __shfl_xor(zv2, 1); zv2 += __shfl_xor(zv2, 2);
        zv2 += __shfl_xor(zv2, 4); zv2 += __shfl_xor(zv2, 8);
        zz[ti] = zv2;
    }
    // zs4 rows used below are written/read by the same 16-lane group (same wave) -> no barrier

    // ---- phase D: scores z@E[s]^T, running (min1,min2,kmin) per t ----
    float m1[4], m2[4]; int k1[4];
    #pragma unroll
    for (int ti = 0; ti < 4; ++ti) { m1[ti] = FLT_MAX; m2[ti] = FLT_MAX; k1[ti] = 0x7fffffff; }

    for (int kk = 0; kk < KN; kk += 128) {
        __syncthreads();                       // all reads of A4 (x/W or prev E chunk) done
        #pragma unroll
        for (int r = 0; r < 8; ++r) {          // stage E chunk (128x64)
            int i = r * 256 + tid;
            es4[(i >> 4) * 17 + (i & 15)] = Eg4[(s * KN + kk) * 16 + i];
        }
        if (tid < 128) e2s[tid] = ws[WS_E2 + s * KN + kk + tid];
        __syncthreads();

        float acc[4][8];
        #pragma unroll
        for (int ti = 0; ti < 4; ++ti)
            #pragma unroll
            for (int j = 0; j < 8; ++j) acc[ti][j] = 0.f;

        #pragma unroll
        for (int c = 0; c < 16; ++c) {
            float4 zv[4], ev[8];
            #pragma unroll
            for (int ti = 0; ti < 4; ++ti) zv[ti] = zs4[(tg * 4 + ti) * 17 + c];
            #pragma unroll
            for (int j = 0; j < 8; ++j) ev[j] = es4[(lg + 16 * j) * 17 + c];
            #pragma unroll
            for (int ti = 0; ti < 4; ++ti) {
                #pragma unroll
                for (int j = 0; j < 8; ++j) {
                    float a = acc[ti][j];
                    a = fmaf(zv[ti].x, ev[j].x, a);
                    a = fmaf(zv[ti].y, ev[j].y, a);
                    a = fmaf(zv[ti].z, ev[j].z, a);
                    a = fmaf(zv[ti].w, ev[j].w, a);
                    acc[ti][j] = a;
                }
            }
        }
        #pragma unroll
        for (int ti = 0; ti < 4; ++ti) {
            #pragma unroll
            for (int j = 0; j < 8; ++j) {
                float d2 = fmaf(-2.0f, acc[ti][j], zz[ti]) + e2s[lg + 16 * j];
                int kx = kk + lg + 16 * j;
                if (d2 < m1[ti]) { m2[ti] = m1[ti]; m1[ti] = d2; k1[ti] = kx; }
                else if (d2 < m2[ti]) { m2[ti] = d2; }
            }
        }
    }

    // cross-lane (16 lanes) lexicographic argmin + second-best merge
    #pragma unroll
    for (int mask = 1; mask <= 8; mask <<= 1) {
        #pragma unroll
        for (int ti = 0; ti < 4; ++ti) {
            float om1 = __shfl_xor(m1[ti], mask);
            int   ok1 = __shfl_xor(k1[ti], mask);
            float om2 = __shfl_xor(m2[ti], mask);
            bool better = (om1 < m1[ti]) || (om1 == m1[ti] && ok1 < k1[ti]);
            float nm2 = better ? fminf(m1[ti], om2) : fminf(om1, m2[ti]);
            if (better) { m1[ti] = om1; k1[ti] = ok1; }
            m2[ti] = nm2;
        }
    }
    if (lg == 0) {
        #pragma unroll
        for (int ti = 0; ti < 4; ++ti) {
            int n = n0 + tg * 4 + ti;
            out[2 * (size_t)NN * DN + s * NN + n] = (float)k1[ti];
            if (m2[ti] - m1[ti] < REPAIR_THR) {   // near-tie -> exact fp64 repair
                int idx = atomicAdd((int*)ws, 1);
                if (idx < entcap) ((int*)ws)[WS_ENT + idx] = (s << 14) | n;
            }
        }
    }
}

// ---------------------------------------------------------------- ze --------
// ze[n] = sum_s x[n] * att_s[n]. Deterministic single write, NO atomics.
__global__ void __launch_bounds__(256)
__attribute__((amdgpu_waves_per_eu(4, 4)))
ze_kernel(const float* __restrict__ x, const float* __restrict__ W,
          const float* __restrict__ ws, float* __restrict__ out) {
    __shared__ float4 xs4[1088];       // 64 x 17
    __shared__ float4 ws4[1024];       // 64 x 16
    __shared__ float scl[64], ofl[64];

    const int tid = threadIdx.x;
    const int tg = tid >> 4;
    const int lg = tid & 15;
    const int n0 = blockIdx.x * 64;

    const float4* xg4 = (const float4*)x;
    const float4* Wg4 = (const float4*)W;

    #pragma unroll
    for (int r = 0; r < 4; ++r) {
        int i = r * 256 + tid;
        xs4[(i >> 4) * 17 + (i & 15)] = xg4[n0 * 16 + i];
    }

    float4 zea[4];
    #pragma unroll
    for (int ti = 0; ti < 4; ++ti) zea[ti] = make_float4(0.f, 0.f, 0.f, 0.f);

    for (int s = 0; s < SN; ++s) {
        __syncthreads();
        #pragma unroll
        for (int r = 0; r < 4; ++r) {
            int i = r * 256 + tid;
            ws4[i] = Wg4[s * 1024 + i];
        }
        if (tid < 64) { scl[tid] = ws[WS_SCL + s * 64 + tid]; ofl[tid] = ws[WS_OFF + s * 64 + tid]; }
        __syncthreads();

        float pa[4][4];
        #pragma unroll
        for (int ti = 0; ti < 4; ++ti)
            #pragma unroll
            for (int j = 0; j < 4; ++j) pa[ti][j] = 0.f;

        #pragma unroll
        for (int c = 0; c < 16; ++c) {
            float4 xv[4], wv[4];
            #pragma unroll
            for (int ti = 0; ti < 4; ++ti) xv[ti] = xs4[(tg * 4 + ti) * 17 + c];
            #pragma unroll
            for (int dd = 0; dd < 4; ++dd) wv[dd] = ws4[(c * 4 + dd) * 16 + lg];
            #pragma unroll
            for (int ti = 0; ti < 4; ++ti) {
                float a0 = pa[ti][0], a1 = pa[ti][1], a2 = pa[ti][2], a3 = pa[ti][3];
                a0 = fmaf(xv[ti].x, wv[0].x, a0); a0 = fmaf(xv[ti].y, wv[1].x, a0);
                a0 = fmaf(xv[ti].z, wv[2].x, a0); a0 = fmaf(xv[ti].w, wv[3].x, a0);
                a1 = fmaf(xv[ti].x, wv[0].y, a1); a1 = fmaf(xv[ti].y, wv[1].y, a1);
                a1 = fmaf(xv[ti].z, wv[2].y, a1); a1 = fmaf(xv[ti].w, wv[3].y, a1);
                a2 = fmaf(xv[ti].x, wv[0].z, a2); a2 = fmaf(xv[ti].y, wv[1].z, a2);
                a2 = fmaf(xv[ti].z, wv[2].z, a2); a2 = fmaf(xv[ti].w, wv[3].z, a2);
                a3 = fmaf(xv[ti].x, wv[0].w, a3); a3 = fmaf(xv[ti].y, wv[1].w, a3);
                a3 = fmaf(xv[ti].z, wv[2].w, a3); a3 = fmaf(xv[ti].w, wv[3].w, a3);
                pa[ti][0] = a0; pa[ti][1] = a1; pa[ti][2] = a2; pa[ti][3] = a3;
            }
        }

        float s0 = scl[lg * 4 + 0], s1 = scl[lg * 4 + 1], s2 = scl[lg * 4 + 2], s3 = scl[lg * 4 + 3];
        float o0 = ofl[lg * 4 + 0], o1 = ofl[lg * 4 + 1], o2 = ofl[lg * 4 + 2], o3 = ofl[lg * 4 + 3];
        #pragma unroll
        for (int ti = 0; ti < 4; ++ti) {
            int t = tg * 4 + ti;
            float v0 = fmaf(pa[ti][0], s0, o0);
            float v1 = fmaf(pa[ti][1], s1, o1);
            float v2 = fmaf(pa[ti][2], s2, o2);
            float v3 = fmaf(pa[ti][3], s3, o3);
            float mx = fmaxf(fmaxf(v0, v1), fmaxf(v2, v3));
            mx = fmaxf(mx, __shfl_xor(mx, 1)); mx = fmaxf(mx, __shfl_xor(mx, 2));
            mx = fmaxf(mx, __shfl_xor(mx, 4)); mx = fmaxf(mx, __shfl_xor(mx, 8));
            float e0 = expf(v0 - mx), e1 = expf(v1 - mx), e2v = expf(v2 - mx), e3 = expf(v3 - mx);
            float sm = e0 + e1 + e2v + e3;
            sm += __shfl_xor(sm, 1); sm += __shfl_xor(sm, 2);
            sm += __shfl_xor(sm, 4); sm += __shfl_xor(sm, 8);
            float inv = 1.0f / sm;
            float4 xv = xs4[t * 17 + lg];
            zea[ti].x += xv.x * (e0 * inv);
            zea[ti].y += xv.y * (e1 * inv);
            zea[ti].z += xv.z * (e2v * inv);
            zea[ti].w += xv.w * (e3 * inv);
        }
    }

    float4* out4 = (float4*)out;
    #pragma unroll
    for (int ti = 0; ti < 4; ++ti) {
        int n = n0 + tg * 4 + ti;
        out4[(size_t)NN * 16 + n * 16 + lg] = zea[ti];
    }
}

// ---------------------------------------------------------------- repair ----
__global__ void repair_kernel(const float* __restrict__ x, const float* __restrict__ W,
                              const float* __restrict__ b, const float* __restrict__ gamma,
                              const float* __restrict__ beta, const float* __restrict__ bmean,
                              const float* __restrict__ bvar, const float* __restrict__ E,
                              float* __restrict__ ws, float* __restrict__ out, int entcap) {
    __shared__ double zd[64];
    __shared__ double red[256];
    __shared__ int redk[256];
    __shared__ double zzsh;
    int cnt = ((int*)ws)[0]; if (cnt > entcap) cnt = entcap;
    const int tid = threadIdx.x;
    for (int idx = blockIdx.x; idx < cnt; idx += gridDim.x) {
        int code = ((int*)ws)[WS_ENT + idx];
        int s = code >> 14, n = code & (NN - 1);
        int e = tid & 63, q = tid >> 6;
        double p = 0.0;
        for (int d = q * 16; d < q * 16 + 16; ++d)
            p = fma((double)x[n * 64 + d], (double)W[((size_t)s * 64 + d) * 64 + e], p);
        red[tid] = p;
        __syncthreads();
        if (tid < 64) {
            double proj = (red[tid] + red[tid + 64]) + (red[tid + 128] + red[tid + 192]);
            double inv = 1.0 / sqrt((double)bvar[s * 64 + e] + 0.001);
            double bn = (double)gamma[s * 64 + e] * ((proj + (double)b[s * 64 + e]) - (double)bmean[s * 64 + e]) * inv
                      + (double)beta[s * 64 + e];
            zd[e] = bn;
        }
        __syncthreads();
        if (tid == 0) {
            double m = zd[0];
            for (int i = 1; i < 64; ++i) m = fmax(m, zd[i]);
            double sm = 0.0;
            for (int i = 0; i < 64; ++i) { double t = exp(zd[i] - m); zd[i] = t; sm += t; }
            double zzv = 0.0;
            for (int i = 0; i < 64; ++i) { double z = (double)x[n * 64 + i] * (zd[i] / sm); zd[i] = z; zzv = fma(z, z, zzv); }
            zzsh = zzv;
        }
        __syncthreads();
        double bv = DBL_MAX; int bk = 1 << 30;
        for (int k = tid; k < KN; k += 256) {
            const float* er = E + ((size_t)s * KN + k) * 64;
            double dot = 0.0, e2 = 0.0;
            for (int d = 0; d < 64; ++d) { double ed = (double)er[d]; dot = fma(zd[d], ed, dot); e2 = fma(ed, ed, e2); }
            double d2 = (zzsh - 2.0 * dot) + e2;
            if (d2 < bv) { bv = d2; bk = k; }
        }
        red[tid] = bv; redk[tid] = bk;
        __syncthreads();
        if (tid == 0) {
            double m = red[0]; int mk = redk[0];
            for (int i = 1; i < 256; ++i)
                if (red[i] < m || (red[i] == m && redk[i] < mk)) { m = red[i]; mk = redk[i]; }
            out[2 * (size_t)NN * 64 + s * NN + n] = (float)mk;
        }
        __syncthreads();
    }
}

// ---------------------------------------------------------------- gather ----
__global__ void gather_kernel(const float* __restrict__ E, float* __restrict__ out) {
    const int tid = threadIdx.x;
    const int ni = tid >> 4, dq = tid & 15;
    const int n = blockIdx.x * 16 + ni;
    const float4* Eg4 = (const float4*)E;
    float4 a = make_float4(0.f, 0.f, 0.f, 0.f);
    #pragma unroll
    for (int s = 0; s < SN; ++s) {
        int k = (int)(out[2 * (size_t)NN * DN + s * NN + n] + 0.5f);
        float4 e = Eg4[((size_t)s * KN + k) * 16 + dq];
        a.x += e.x; a.y += e.y; a.z += e.z; a.w += e.w;
    }
    ((float4*)out)[(size_t)n * 16 + dq] = a;
}

// ---------------------------------------------------------------- launch ----
extern "C" void kernel_launch(void* const* d_in, const int* in_sizes, int n_in,
                              void* d_out, int out_size, void* d_ws, size_t ws_size,
                              hipStream_t stream) {
    const float* x     = (const float*)d_in[0];
    const float* W     = (const float*)d_in[1];
    const float* b     = (const float*)d_in[2];
    const float* gamma = (const float*)d_in[3];
    const float* beta  = (const float*)d_in[4];
    const float* bmean = (const float*)d_in[5];
    const float* bvar  = (const float*)d_in[6];
    const float* E     = (const float*)d_in[7];
    float* out = (float*)d_out;
    float* ws  = (float*)d_ws;

    long avail = (long)(ws_size / 4) - WS_ENT - 16;
    if (avail < 0) avail = 0;
    int entcap = (int)(avail > MAXFLAG ? MAXFLAG : avail);

    hipMemsetAsync(d_ws, 0, 64, stream);                          // zero flag counter
    prep_kernel<<<18, 256, 0, stream>>>(b, gamma, beta, bmean, bvar, E, ws);
    main_kernel<<<2048, 256, 0, stream>>>(x, W, E, ws, out, entcap);
    ze_kernel<<<256, 256, 0, stream>>>(x, W, ws, out);
    repair_kernel<<<256, 256, 0, stream>>>(x, W, b, gamma, beta, bmean, bvar, E, ws, out, entcap);
    gather_kernel<<<1024, 256, 0, stream>>>(E, out);
}

// Round 6
// 5427.946 us; speedup vs baseline: 1.0480x; 1.0466x over previous
//
#include <hip/hip_runtime.h>
#include <cfloat>
#include <cmath>

// Problem constants
#define SN 8
#define DN 64
#define KN 512
#define NN 16384            // B*T
#define REPAIR_THR 1e-2f    // fp32 d2 noise ~1e-5; 1000x margin
#define MAXFLAG 65536

// workspace layout (float indices)
#define WS_CNT 0
#define WS_SCL 16
#define WS_OFF (16 + SN*DN)           // 528
#define WS_E2  (WS_OFF + SN*DN)       // 1040
#define WS_ENT (WS_E2 + SN*KN)        // 5136 (ints)

// ---------------------------------------------------------------- prep ------
__global__ void prep_kernel(const float* __restrict__ b, const float* __restrict__ gamma,
                            const float* __restrict__ beta, const float* __restrict__ bmean,
                            const float* __restrict__ bvar, const float* __restrict__ E,
                            float* __restrict__ ws) {
    int tid = blockIdx.x * 256 + threadIdx.x;
    if (tid < SN * KN) {                       // ||E_k||^2 in fp64, stored fp32
        const float* er = E + (size_t)tid * DN;
        double a = 0.0;
        for (int d = 0; d < DN; ++d) { double v = (double)er[d]; a = fma(v, v, a); }
        ws[WS_E2 + tid] = (float)a;
    }
    int u = tid - SN * KN;
    if (u >= 0 && u < SN * DN) {               // fold BN+bias: bn = proj*scl + off
        double inv = 1.0 / sqrt((double)bvar[u] + 0.001);
        double sc  = (double)gamma[u] * inv;
        ws[WS_SCL + u] = (float)sc;
        ws[WS_OFF + u] = (float)(((double)b[u] - (double)bmean[u]) * sc + (double)beta[u]);
    }
}

// ======================= all-scalar macro kit ================================
// NO private arrays anywhere in hot paths: r1-r5's 7-16 GB of HBM traffic was
// private arrays (acc/ev/zv/pa) demoted to scratch (SROA failure under the
// unroll nest) streaming to HBM. Named scalars cannot be demoted.

// outer-product update: P(row of 4 accs as float4) += X(4 k-elems) * w0..w3 cols
#define PC_UPD(P, X) \
    P.x = fmaf(X.x, w0.x, P.x); P.x = fmaf(X.y, w1.x, P.x); P.x = fmaf(X.z, w2.x, P.x); P.x = fmaf(X.w, w3.x, P.x); \
    P.y = fmaf(X.x, w0.y, P.y); P.y = fmaf(X.y, w1.y, P.y); P.y = fmaf(X.z, w2.y, P.y); P.y = fmaf(X.w, w3.y, P.y); \
    P.z = fmaf(X.x, w0.z, P.z); P.z = fmaf(X.y, w1.z, P.z); P.z = fmaf(X.z, w2.z, P.z); P.z = fmaf(X.w, w3.z, P.z); \
    P.w = fmaf(X.x, w0.w, P.w); P.w = fmaf(X.y, w1.w, P.w); P.w = fmaf(X.z, w2.w, P.w); P.w = fmaf(X.w, w3.w, P.w)

// dot4 accumulate: A += dot(Z, Ev)
#define D4(A, Z, Ev) \
    A = fmaf(Z.x, Ev.x, A); A = fmaf(Z.y, Ev.y, A); A = fmaf(Z.z, Ev.z, A); A = fmaf(Z.w, Ev.w, A)

// d2 + running (min1,min2,argmin) update for acc A at column j=J
#define DMIN(A, J, ZZ, M1, M2, K1) { \
    float d2v = fmaf(-2.0f, A, ZZ) + e2s[lg + 16 * (J)]; \
    int kxv = kk + lg + 16 * (J); \
    if (d2v < M1) { M2 = M1; M1 = d2v; K1 = kxv; } \
    else if (d2v < M2) { M2 = d2v; } }

// cross-lane lexicographic (min1,k) + min2 merge over xor MASK
#define MMERGE(M1, M2, K1, MASK) { \
    float om1 = __shfl_xor(M1, MASK); \
    int   ok1 = __shfl_xor(K1, MASK); \
    float om2 = __shfl_xor(M2, MASK); \
    bool bt = (om1 < M1) || (om1 == M1 && ok1 < K1); \
    float nm2 = bt ? fminf(M1, om2) : fminf(om1, M2); \
    if (bt) { M1 = om1; K1 = ok1; } \
    M2 = nm2; }

// BN + softmax over 64 (16 lanes x 4) for one row T; writes z to zs4, zz out
#define SOFTZ(P, ZZ, T) { \
    float v0 = fmaf(P.x, s0, o0), v1 = fmaf(P.y, s1, o1); \
    float v2 = fmaf(P.z, s2, o2), v3 = fmaf(P.w, s3, o3); \
    float mxv = fmaxf(fmaxf(v0, v1), fmaxf(v2, v3)); \
    mxv = fmaxf(mxv, __shfl_xor(mxv, 1)); mxv = fmaxf(mxv, __shfl_xor(mxv, 2)); \
    mxv = fmaxf(mxv, __shfl_xor(mxv, 4)); mxv = fmaxf(mxv, __shfl_xor(mxv, 8)); \
    float ex0 = expf(v0 - mxv), ex1 = expf(v1 - mxv), ex2 = expf(v2 - mxv), ex3 = expf(v3 - mxv); \
    float smv = ex0 + ex1 + ex2 + ex3; \
    smv += __shfl_xor(smv, 1); smv += __shfl_xor(smv, 2); \
    smv += __shfl_xor(smv, 4); smv += __shfl_xor(smv, 8); \
    float invv = 1.0f / smv; \
    float4 xvv = xs4[(T) * 17 + lg]; \
    float zr0 = xvv.x * (ex0 * invv), zr1 = xvv.y * (ex1 * invv); \
    float zr2 = xvv.z * (ex2 * invv), zr3 = xvv.w * (ex3 * invv); \
    zs4[(T) * 17 + lg] = make_float4(zr0, zr1, zr2, zr3); \
    float zsq = zr0 * zr0 + zr1 * zr1 + zr2 * zr2 + zr3 * zr3; \
    zsq += __shfl_xor(zsq, 1); zsq += __shfl_xor(zsq, 2); \
    zsq += __shfl_xor(zsq, 4); zsq += __shfl_xor(zsq, 8); \
    ZZ = zsq; }

// BN + softmax + accumulate x*att into ZEA (float4), for ze_kernel
#define SOFTZE(P, ZEA, T) { \
    float v0 = fmaf(P.x, s0, o0), v1 = fmaf(P.y, s1, o1); \
    float v2 = fmaf(P.z, s2, o2), v3 = fmaf(P.w, s3, o3); \
    float mxv = fmaxf(fmaxf(v0, v1), fmaxf(v2, v3)); \
    mxv = fmaxf(mxv, __shfl_xor(mxv, 1)); mxv = fmaxf(mxv, __shfl_xor(mxv, 2)); \
    mxv = fmaxf(mxv, __shfl_xor(mxv, 4)); mxv = fmaxf(mxv, __shfl_xor(mxv, 8)); \
    float ex0 = expf(v0 - mxv), ex1 = expf(v1 - mxv), ex2 = expf(v2 - mxv), ex3 = expf(v3 - mxv); \
    float smv = ex0 + ex1 + ex2 + ex3; \
    smv += __shfl_xor(smv, 1); smv += __shfl_xor(smv, 2); \
    smv += __shfl_xor(smv, 4); smv += __shfl_xor(smv, 8); \
    float invv = 1.0f / smv; \
    float4 xvv = xs4[(T) * 17 + lg]; \
    ZEA.x += xvv.x * (ex0 * invv); ZEA.y += xvv.y * (ex1 * invv); \
    ZEA.z += xvv.z * (ex2 * invv); ZEA.w += xvv.w * (ex3 * invv); }

// ---------------------------------------------------------------- main ------
// grid 2048 = (s = bid&7 [XCD-pinned], ntile = bid>>3). 256 thr = 16 tg x 16 lg,
// 64 positions/block, one s per block. All-scalar hot path (see macro kit).
__global__ void __launch_bounds__(256, 2)
main_kernel(const float* __restrict__ x, const float* __restrict__ W,
            const float* __restrict__ E, float* __restrict__ ws,
            float* __restrict__ out, int entcap) {
    __shared__ float4 A4[2176];        // 34.8 KB union: {x-tile + W} | E-chunk
    __shared__ float4 zs4[1088];       // 17.4 KB z tile (stride 17)
    __shared__ float scl[64], ofl[64], e2s[128];

    const int tid = threadIdx.x;
    const int tg = tid >> 4;
    const int lg = tid & 15;
    const int s  = blockIdx.x & 7;
    const int n0 = (blockIdx.x >> 3) * 64;

    const float4* xg4 = (const float4*)x;
    const float4* Wg4 = (const float4*)W;
    const float4* Eg4 = (const float4*)E;

    float4* xs4 = A4;                  // 64 rows x stride 17
    float4* ws4 = A4 + 1088;           // 64 rows x stride 16
    float4* es4 = A4;                  // phase D: 128 rows x stride 17

    #pragma unroll
    for (int r = 0; r < 4; ++r) {
        int i = r * 256 + tid;
        xs4[(i >> 4) * 17 + (i & 15)] = xg4[n0 * 16 + i];
        ws4[i] = Wg4[s * 1024 + i];
    }
    if (tid < 64) { scl[tid] = ws[WS_SCL + s * 64 + tid]; ofl[tid] = ws[WS_OFF + s * 64 + tid]; }
    __syncthreads();

    // ---- phase C: proj = x @ W[s], rows tg*4+0..3, cols lg*4+0..3 ----
    float4 p0 = {0,0,0,0}, p1 = {0,0,0,0}, p2 = {0,0,0,0}, p3 = {0,0,0,0};
    #pragma unroll
    for (int c = 0; c < 16; ++c) {
        float4 x0 = xs4[(tg * 4 + 0) * 17 + c];
        float4 x1 = xs4[(tg * 4 + 1) * 17 + c];
        float4 x2 = xs4[(tg * 4 + 2) * 17 + c];
        float4 x3 = xs4[(tg * 4 + 3) * 17 + c];
        float4 w0 = ws4[(c * 4 + 0) * 16 + lg];
        float4 w1 = ws4[(c * 4 + 1) * 16 + lg];
        float4 w2 = ws4[(c * 4 + 2) * 16 + lg];
        float4 w3 = ws4[(c * 4 + 3) * 16 + lg];
        PC_UPD(p0, x0); PC_UPD(p1, x1); PC_UPD(p2, x2); PC_UPD(p3, x3);
    }

    // ---- BN + softmax + z ----
    float s0 = scl[lg * 4 + 0], s1 = scl[lg * 4 + 1], s2 = scl[lg * 4 + 2], s3 = scl[lg * 4 + 3];
    float o0 = ofl[lg * 4 + 0], o1 = ofl[lg * 4 + 1], o2 = ofl[lg * 4 + 2], o3 = ofl[lg * 4 + 3];
    float zz0, zz1, zz2, zz3;
    SOFTZ(p0, zz0, tg * 4 + 0);
    SOFTZ(p1, zz1, tg * 4 + 1);
    SOFTZ(p2, zz2, tg * 4 + 2);
    SOFTZ(p3, zz3, tg * 4 + 3);
    // zs4 rows below are written/read by the same 16-lane group (same wave): no barrier

    // ---- phase D: z @ E[s]^T with running (min1,min2,argmin) ----
    float m1_0 = FLT_MAX, m2_0 = FLT_MAX; int k1_0 = 0x7fffffff;
    float m1_1 = FLT_MAX, m2_1 = FLT_MAX; int k1_1 = 0x7fffffff;
    float m1_2 = FLT_MAX, m2_2 = FLT_MAX; int k1_2 = 0x7fffffff;
    float m1_3 = FLT_MAX, m2_3 = FLT_MAX; int k1_3 = 0x7fffffff;

    for (int kk = 0; kk < KN; kk += 128) {
        __syncthreads();
        #pragma unroll
        for (int r = 0; r < 8; ++r) {
            int i = r * 256 + tid;
            es4[(i >> 4) * 17 + (i & 15)] = Eg4[(s * KN + kk) * 16 + i];
        }
        if (tid < 128) e2s[tid] = ws[WS_E2 + s * KN + kk + tid];
        __syncthreads();

        float a00 = 0, a01 = 0, a02 = 0, a03 = 0, a04 = 0, a05 = 0, a06 = 0, a07 = 0;
        float a10 = 0, a11 = 0, a12 = 0, a13 = 0, a14 = 0, a15 = 0, a16 = 0, a17 = 0;
        float a20 = 0, a21 = 0, a22 = 0, a23 = 0, a24 = 0, a25 = 0, a26 = 0, a27 = 0;
        float a30 = 0, a31 = 0, a32 = 0, a33 = 0, a34 = 0, a35 = 0, a36 = 0, a37 = 0;

        #pragma unroll
        for (int c = 0; c < 16; ++c) {
            float4 z0 = zs4[(tg * 4 + 0) * 17 + c];
            float4 z1 = zs4[(tg * 4 + 1) * 17 + c];
            float4 z2 = zs4[(tg * 4 + 2) * 17 + c];
            float4 z3 = zs4[(tg * 4 + 3) * 17 + c];
            float4 e0 = es4[(lg +   0) * 17 + c];
            float4 e1 = es4[(lg +  16) * 17 + c];
            float4 e2 = es4[(lg +  32) * 17 + c];
            float4 e3 = es4[(lg +  48) * 17 + c];
            float4 e4 = es4[(lg +  64) * 17 + c];
            float4 e5 = es4[(lg +  80) * 17 + c];
            float4 e6 = es4[(lg +  96) * 17 + c];
            float4 e7 = es4[(lg + 112) * 17 + c];
            D4(a00, z0, e0); D4(a01, z0, e1); D4(a02, z0, e2); D4(a03, z0, e3);
            D4(a04, z0, e4); D4(a05, z0, e5); D4(a06, z0, e6); D4(a07, z0, e7);
            D4(a10, z1, e0); D4(a11, z1, e1); D4(a12, z1, e2); D4(a13, z1, e3);
            D4(a14, z1, e4); D4(a15, z1, e5); D4(a16, z1, e6); D4(a17, z1, e7);
            D4(a20, z2, e0); D4(a21, z2, e1); D4(a22, z2, e2); D4(a23, z2, e3);
            D4(a24, z2, e4); D4(a25, z2, e5); D4(a26, z2, e6); D4(a27, z2, e7);
            D4(a30, z3, e0); D4(a31, z3, e1); D4(a32, z3, e2); D4(a33, z3, e3);
            D4(a34, z3, e4); D4(a35, z3, e5); D4(a36, z3, e6); D4(a37, z3, e7);
        }
        DMIN(a00, 0, zz0, m1_0, m2_0, k1_0); DMIN(a01, 1, zz0, m1_0, m2_0, k1_0);
        DMIN(a02, 2, zz0, m1_0, m2_0, k1_0); DMIN(a03, 3, zz0, m1_0, m2_0, k1_0);
        DMIN(a04, 4, zz0, m1_0, m2_0, k1_0); DMIN(a05, 5, zz0, m1_0, m2_0, k1_0);
        DMIN(a06, 6, zz0, m1_0, m2_0, k1_0); DMIN(a07, 7, zz0, m1_0, m2_0, k1_0);
        DMIN(a10, 0, zz1, m1_1, m2_1, k1_1); DMIN(a11, 1, zz1, m1_1, m2_1, k1_1);
        DMIN(a12, 2, zz1, m1_1, m2_1, k1_1); DMIN(a13, 3, zz1, m1_1, m2_1, k1_1);
        DMIN(a14, 4, zz1, m1_1, m2_1, k1_1); DMIN(a15, 5, zz1, m1_1, m2_1, k1_1);
        DMIN(a16, 6, zz1, m1_1, m2_1, k1_1); DMIN(a17, 7, zz1, m1_1, m2_1, k1_1);
        DMIN(a20, 0, zz2, m1_2, m2_2, k1_2); DMIN(a21, 1, zz2, m1_2, m2_2, k1_2);
        DMIN(a22, 2, zz2, m1_2, m2_2, k1_2); DMIN(a23, 3, zz2, m1_2, m2_2, k1_2);
        DMIN(a24, 4, zz2, m1_2, m2_2, k1_2); DMIN(a25, 5, zz2, m1_2, m2_2, k1_2);
        DMIN(a26, 6, zz2, m1_2, m2_2, k1_2); DMIN(a27, 7, zz2, m1_2, m2_2, k1_2);
        DMIN(a30, 0, zz3, m1_3, m2_3, k1_3); DMIN(a31, 1, zz3, m1_3, m2_3, k1_3);
        DMIN(a32, 2, zz3, m1_3, m2_3, k1_3); DMIN(a33, 3, zz3, m1_3, m2_3, k1_3);
        DMIN(a34, 4, zz3, m1_3, m2_3, k1_3); DMIN(a35, 5, zz3, m1_3, m2_3, k1_3);
        DMIN(a36, 6, zz3, m1_3, m2_3, k1_3); DMIN(a37, 7, zz3, m1_3, m2_3, k1_3);
    }

    #pragma unroll
    for (int mask = 1; mask <= 8; mask <<= 1) {
        MMERGE(m1_0, m2_0, k1_0, mask);
        MMERGE(m1_1, m2_1, k1_1, mask);
        MMERGE(m1_2, m2_2, k1_2, mask);
        MMERGE(m1_3, m2_3, k1_3, mask);
    }
    if (lg == 0) {
        float* zko = out + 2 * (size_t)NN * DN + s * NN + n0 + tg * 4;
        zko[0] = (float)k1_0; zko[1] = (float)k1_1;
        zko[2] = (float)k1_2; zko[3] = (float)k1_3;
        int flg0 = (m2_0 - m1_0 < REPAIR_THR) ? 1 : 0;
        int flg1 = (m2_1 - m1_1 < REPAIR_THR) ? 1 : 0;
        int flg2 = (m2_2 - m1_2 < REPAIR_THR) ? 1 : 0;
        int flg3 = (m2_3 - m1_3 < REPAIR_THR) ? 1 : 0;
        if (flg0 + flg1 + flg2 + flg3) {
            int base = atomicAdd((int*)ws, flg0 + flg1 + flg2 + flg3);
            int n = n0 + tg * 4;
            if (flg0 && base < entcap) ((int*)ws)[WS_ENT + base++] = (s << 14) | (n + 0);
            if (flg1 && base < entcap) ((int*)ws)[WS_ENT + base++] = (s << 14) | (n + 1);
            if (flg2 && base < entcap) ((int*)ws)[WS_ENT + base++] = (s << 14) | (n + 2);
            if (flg3 && base < entcap) ((int*)ws)[WS_ENT + base++] = (s << 14) | (n + 3);
        }
    }
}

// ---------------------------------------------------------------- ze --------
// ze[n] = sum_s x[n] * att_s[n]; all-scalar, deterministic, no atomics.
__global__ void __launch_bounds__(256, 2)
ze_kernel(const float* __restrict__ x, const float* __restrict__ W,
          const float* __restrict__ ws, float* __restrict__ out) {
    __shared__ float4 xs4[1088];       // 64 x 17
    __shared__ float4 ws4[1024];       // 64 x 16
    __shared__ float scl[64], ofl[64];

    const int tid = threadIdx.x;
    const int tg = tid >> 4;
    const int lg = tid & 15;
    const int n0 = blockIdx.x * 64;

    const float4* xg4 = (const float4*)x;
    const float4* Wg4 = (const float4*)W;

    #pragma unroll
    for (int r = 0; r < 4; ++r) {
        int i = r * 256 + tid;
        xs4[(i >> 4) * 17 + (i & 15)] = xg4[n0 * 16 + i];
    }

    float4 ze0 = {0,0,0,0}, ze1 = {0,0,0,0}, ze2 = {0,0,0,0}, ze3 = {0,0,0,0};

    for (int s = 0; s < SN; ++s) {
        __syncthreads();
        #pragma unroll
        for (int r = 0; r < 4; ++r) {
            int i = r * 256 + tid;
            ws4[i] = Wg4[s * 1024 + i];
        }
        if (tid < 64) { scl[tid] = ws[WS_SCL + s * 64 + tid]; ofl[tid] = ws[WS_OFF + s * 64 + tid]; }
        __syncthreads();

        float4 p0 = {0,0,0,0}, p1 = {0,0,0,0}, p2 = {0,0,0,0}, p3 = {0,0,0,0};
        #pragma unroll
        for (int c = 0; c < 16; ++c) {
            float4 x0 = xs4[(tg * 4 + 0) * 17 + c];
            float4 x1 = xs4[(tg * 4 + 1) * 17 + c];
            float4 x2 = xs4[(tg * 4 + 2) * 17 + c];
            float4 x3 = xs4[(tg * 4 + 3) * 17 + c];
            float4 w0 = ws4[(c * 4 + 0) * 16 + lg];
            float4 w1 = ws4[(c * 4 + 1) * 16 + lg];
            float4 w2 = ws4[(c * 4 + 2) * 16 + lg];
            float4 w3 = ws4[(c * 4 + 3) * 16 + lg];
            PC_UPD(p0, x0); PC_UPD(p1, x1); PC_UPD(p2, x2); PC_UPD(p3, x3);
        }

        float s0 = scl[lg * 4 + 0], s1 = scl[lg * 4 + 1], s2 = scl[lg * 4 + 2], s3 = scl[lg * 4 + 3];
        float o0 = ofl[lg * 4 + 0], o1 = ofl[lg * 4 + 1], o2 = ofl[lg * 4 + 2], o3 = ofl[lg * 4 + 3];
        SOFTZE(p0, ze0, tg * 4 + 0);
        SOFTZE(p1, ze1, tg * 4 + 1);
        SOFTZE(p2, ze2, tg * 4 + 2);
        SOFTZE(p3, ze3, tg * 4 + 3);
    }

    float4* out4 = (float4*)out;
    out4[(size_t)NN * 16 + (size_t)(n0 + tg * 4 + 0) * 16 + lg] = ze0;
    out4[(size_t)NN * 16 + (size_t)(n0 + tg * 4 + 1) * 16 + lg] = ze1;
    out4[(size_t)NN * 16 + (size_t)(n0 + tg * 4 + 2) * 16 + lg] = ze2;
    out4[(size_t)NN * 16 + (size_t)(n0 + tg * 4 + 3) * 16 + lg] = ze3;
}

// ---------------------------------------------------------------- repair ----
// Exact fp64 recompute for flagged near-tie positions; fixes z_k only
// (runs BEFORE gather_kernel, which derives z_q from final z_k).
__global__ void repair_kernel(const float* __restrict__ x, const float* __restrict__ W,
                              const float* __restrict__ b, const float* __restrict__ gamma,
                              const float* __restrict__ beta, const float* __restrict__ bmean,
                              const float* __restrict__ bvar, const float* __restrict__ E,
                              float* __restrict__ ws, float* __restrict__ out, int entcap) {
    __shared__ double zd[64];
    __shared__ double red[256];
    __shared__ int redk[256];
    __shared__ double zzsh;
    int cnt = ((int*)ws)[0]; if (cnt > entcap) cnt = entcap;
    const int tid = threadIdx.x;
    for (int idx = blockIdx.x; idx < cnt; idx += gridDim.x) {
        int code = ((int*)ws)[WS_ENT + idx];
        int s = code >> 14, n = code & (NN - 1);
        int e = tid & 63, q = tid >> 6;
        double p = 0.0;
        for (int d = q * 16; d < q * 16 + 16; ++d)
            p = fma((double)x[n * 64 + d], (double)W[((size_t)s * 64 + d) * 64 + e], p);
        red[tid] = p;
        __syncthreads();
        if (tid < 64) {
            double proj = (red[tid] + red[tid + 64]) + (red[tid + 128] + red[tid + 192]);
            double inv = 1.0 / sqrt((double)bvar[s * 64 + e] + 0.001);
            double bn = (double)gamma[s * 64 + e] * ((proj + (double)b[s * 64 + e]) - (double)bmean[s * 64 + e]) * inv
                      + (double)beta[s * 64 + e];
            zd[e] = bn;
        }
        __syncthreads();
        if (tid == 0) {
            double m = zd[0];
            for (int i = 1; i < 64; ++i) m = fmax(m, zd[i]);
            double sm = 0.0;
            for (int i = 0; i < 64; ++i) { double t = exp(zd[i] - m); zd[i] = t; sm += t; }
            double zzv = 0.0;
            for (int i = 0; i < 64; ++i) { double z = (double)x[n * 64 + i] * (zd[i] / sm); zd[i] = z; zzv = fma(z, z, zzv); }
            zzsh = zzv;
        }
        __syncthreads();
        double bv = DBL_MAX; int bk = 1 << 30;
        for (int k = tid; k < KN; k += 256) {
            const float* er = E + ((size_t)s * KN + k) * 64;
            double dot = 0.0, e2 = 0.0;
            for (int d = 0; d < 64; ++d) { double ed = (double)er[d]; dot = fma(zd[d], ed, dot); e2 = fma(ed, ed, e2); }
            double d2 = (zzsh - 2.0 * dot) + e2;
            if (d2 < bv) { bv = d2; bk = k; }
        }
        red[tid] = bv; redk[tid] = bk;
        __syncthreads();
        if (tid == 0) {
            double m = red[0]; int mk = redk[0];
            for (int i = 1; i < 256; ++i)
                if (red[i] < m || (red[i] == m && redk[i] < mk)) { m = red[i]; mk = redk[i]; }
            out[2 * (size_t)NN * 64 + s * NN + n] = (float)mk;
        }
        __syncthreads();
    }
}

// ---------------------------------------------------------------- gather ----
// zq[n] = sum_s E[s, zk[s,n]] — deterministic, reads final z_k.
__global__ void gather_kernel(const float* __restrict__ E, float* __restrict__ out) {
    const int tid = threadIdx.x;
    const int ni = tid >> 4, dq = tid & 15;
    const int n = blockIdx.x * 16 + ni;
    const float4* Eg4 = (const float4*)E;
    float4 a = make_float4(0.f, 0.f, 0.f, 0.f);
    #pragma unroll
    for (int s = 0; s < SN; ++s) {
        int k = (int)(out[2 * (size_t)NN * DN + s * NN + n] + 0.5f);
        float4 e = Eg4[((size_t)s * KN + k) * 16 + dq];
        a.x += e.x; a.y += e.y; a.z += e.z; a.w += e.w;
    }
    ((float4*)out)[(size_t)n * 16 + dq] = a;
}

// ---------------------------------------------------------------- launch ----
extern "C" void kernel_launch(void* const* d_in, const int* in_sizes, int n_in,
                              void* d_out, int out_size, void* d_ws, size_t ws_size,
                              hipStream_t stream) {
    const float* x     = (const float*)d_in[0];
    const float* W     = (const float*)d_in[1];
    const float* b     = (const float*)d_in[2];
    const float* gamma = (const float*)d_in[3];
    const float* beta  = (const float*)d_in[4];
    const float* bmean = (const float*)d_in[5];
    const float* bvar  = (const float*)d_in[6];
    const float* E     = (const float*)d_in[7];
    float* out = (float*)d_out;
    float* ws  = (float*)d_ws;

    long avail = (long)(ws_size / 4) - WS_ENT - 16;
    if (avail < 0) avail = 0;
    int entcap = (int)(avail > MAXFLAG ? MAXFLAG : avail);

    hipMemsetAsync(d_ws, 0, 64, stream);                          // zero flag counter
    prep_kernel<<<18, 256, 0, stream>>>(b, gamma, beta, bmean, bvar, E, ws);
    main_kernel<<<2048, 256, 0, stream>>>(x, W, E, ws, out, entcap);
    ze_kernel<<<256, 256, 0, stream>>>(x, W, ws, out);
    repair_kernel<<<256, 256, 0, stream>>>(x, W, b, gamma, beta, bmean, bvar, E, ws, out, entcap);
    gather_kernel<<<1024, 256, 0, stream>>>(E, out);
}